// Round 1
// baseline (71.254 us; speedup 1.0000x reference)
//
#include <hip/hip_runtime.h>

#define H 1024
#define L 512
#define V 50257

__device__ __forceinline__ float wave_reduce_sum(float v) {
    #pragma unroll
    for (int o = 32; o > 0; o >>= 1) v += __shfl_xor(v, o, 64);
    return v;
}

// valid on thread 0 only; safe to call repeatedly (trailing barrier)
__device__ __forceinline__ float block_reduce_sum256(float v, float* lds) {
    v = wave_reduce_sum(v);
    int wid = threadIdx.x >> 6, lane = threadIdx.x & 63;
    if (lane == 0) lds[wid] = v;
    __syncthreads();
    float r = 0.f;
    if (threadIdx.x == 0) r = lds[0] + lds[1] + lds[2] + lds[3];
    __syncthreads();
    return r;
}

// scores[l] = attn_w[l,:1024].e + attn_w[l,1024:].h0 + attn_b[l]
__global__ void k_scores(const float* __restrict__ emb, const int* __restrict__ input,
                         const float* __restrict__ hidden, const float* __restrict__ attn_w,
                         const float* __restrict__ attn_b, float* __restrict__ scores) {
    __shared__ float lds[4];
    int l = blockIdx.x, t = threadIdx.x;
    size_t erow = (size_t)input[0] * H;
    const float4* w = (const float4*)(attn_w + (size_t)l * 2 * H);
    float4 a  = w[t];
    float4 b  = w[256 + t];
    float4 ev = ((const float4*)(emb + erow))[t];
    float4 hv = ((const float4*)hidden)[t];
    float acc = a.x*ev.x + a.y*ev.y + a.z*ev.z + a.w*ev.w
              + b.x*hv.x + b.y*hv.y + b.z*hv.z + b.w*hv.w;
    acc = block_reduce_sum256(acc, lds);
    if (t == 0) scores[l] = acc + attn_b[l];
}

// softmax over 512 scores -> attn_weights (written to d_out slot)
__global__ void k_softmax(const float* __restrict__ scores, float* __restrict__ attn_out) {
    __shared__ float lds[8];
    int t = threadIdx.x;
    float x = scores[t];
    float m = x;
    #pragma unroll
    for (int o = 32; o > 0; o >>= 1) m = fmaxf(m, __shfl_xor(m, o, 64));
    if ((t & 63) == 0) lds[t >> 6] = m;
    __syncthreads();
    m = lds[0];
    #pragma unroll
    for (int i = 1; i < 8; ++i) m = fmaxf(m, lds[i]);
    __syncthreads();
    float e = expf(x - m);
    float s = e;
    #pragma unroll
    for (int o = 32; o > 0; o >>= 1) s += __shfl_xor(s, o, 64);
    if ((t & 63) == 0) lds[t >> 6] = s;
    __syncthreads();
    s = 0.f;
    #pragma unroll
    for (int i = 0; i < 8; ++i) s += lds[i];
    attn_out[t] = e / s;
}

// partial[b][h] = sum_{l in chunk b} w[l]*enc[l][h], 32 chunks of 16
__global__ void k_attn_partial(const float* __restrict__ enc, const float* __restrict__ w,
                               float* __restrict__ partial) {
    int b = blockIdx.x, t = threadIdx.x;
    float4 acc = {0.f, 0.f, 0.f, 0.f};
    for (int l = b * 16; l < b * 16 + 16; ++l) {
        float wl = w[l];
        float4 ev = ((const float4*)(enc + (size_t)l * H))[t];
        acc.x += wl * ev.x; acc.y += wl * ev.y; acc.z += wl * ev.z; acc.w += wl * ev.w;
    }
    ((float4*)(partial + (size_t)b * H))[t] = acc;
}

__global__ void k_attn_reduce(const float* __restrict__ partial, float* __restrict__ attn_applied) {
    int h = blockIdx.x * 256 + threadIdx.x;
    float s = 0.f;
    #pragma unroll 8
    for (int p = 0; p < 32; ++p) s += partial[p * H + h];
    attn_applied[h] = s;
}

// x[h] = relu(comb_w[h,:1024].e + comb_w[h,1024:].attn_applied + comb_b[h])
__global__ void k_combine(const float* __restrict__ emb, const int* __restrict__ input,
                          const float* __restrict__ attn_applied, const float* __restrict__ comb_w,
                          const float* __restrict__ comb_b, float* __restrict__ x) {
    __shared__ float lds[4];
    int h = blockIdx.x, t = threadIdx.x;
    size_t erow = (size_t)input[0] * H;
    const float4* w = (const float4*)(comb_w + (size_t)h * 2 * H);
    float4 a  = w[t];
    float4 b  = w[256 + t];
    float4 ev = ((const float4*)(emb + erow))[t];
    float4 av = ((const float4*)attn_applied)[t];
    float acc = a.x*ev.x + a.y*ev.y + a.z*ev.z + a.w*ev.w
              + b.x*av.x + b.y*av.y + b.z*av.z + b.w*av.w;
    acc = block_reduce_sum256(acc, lds);
    if (t == 0) x[h] = fmaxf(acc + comb_b[h], 0.f);
}

// gi[j] = w_ih[j].x + b_ih[j]; gh[j] = w_hh[j].h0 + b_hh[j]
__global__ void k_gigh(const float* __restrict__ w_ih, const float* __restrict__ w_hh,
                       const float* __restrict__ b_ih, const float* __restrict__ b_hh,
                       const float* __restrict__ x, const float* __restrict__ hidden,
                       float* __restrict__ gi, float* __restrict__ gh) {
    __shared__ float lds[4];
    int j = blockIdx.x, t = threadIdx.x;
    float4 wi = ((const float4*)(w_ih + (size_t)j * H))[t];
    float4 wh = ((const float4*)(w_hh + (size_t)j * H))[t];
    float4 xv = ((const float4*)x)[t];
    float4 hv = ((const float4*)hidden)[t];
    float ai = wi.x*xv.x + wi.y*xv.y + wi.z*xv.z + wi.w*xv.w;
    float ah = wh.x*hv.x + wh.y*hv.y + wh.z*hv.z + wh.w*hv.w;
    ai = block_reduce_sum256(ai, lds);
    ah = block_reduce_sum256(ah, lds);
    if (t == 0) { gi[j] = ai + b_ih[j]; gh[j] = ah + b_hh[j]; }
}

__global__ void k_gru(const float* __restrict__ gi, const float* __restrict__ gh,
                      const float* __restrict__ hidden, float* __restrict__ hnew) {
    int h = blockIdx.x * 256 + threadIdx.x;
    float r = 1.f / (1.f + expf(-(gi[h] + gh[h])));
    float z = 1.f / (1.f + expf(-(gi[H + h] + gh[H + h])));
    float n = tanhf(gi[2 * H + h] + r * gh[2 * H + h]);
    hnew[h] = (1.f - z) * n + z * hidden[h];
}

// logits[r] = out_w[r].h_new + out_b[r]  (one row per wave, grid-stride)
__global__ void k_logits(const float* __restrict__ out_w, const float* __restrict__ out_b,
                         const float* __restrict__ hvec, float* __restrict__ logits) {
    int lane = threadIdx.x & 63;
    int gwave = blockIdx.x * 4 + (threadIdx.x >> 6);
    int nwaves = gridDim.x * 4;
    float4 h4[4];
    #pragma unroll
    for (int j = 0; j < 4; ++j) h4[j] = ((const float4*)hvec)[j * 64 + lane];
    for (int r = gwave; r < V; r += nwaves) {
        const float4* row = (const float4*)(out_w + (size_t)r * H);
        float acc = 0.f;
        #pragma unroll
        for (int j = 0; j < 4; ++j) {
            float4 a = row[j * 64 + lane];
            acc += a.x*h4[j].x + a.y*h4[j].y + a.z*h4[j].z + a.w*h4[j].w;
        }
        acc = wave_reduce_sum(acc);
        if (lane == 0) logits[r] = acc + out_b[r];
    }
}

// per-block online (max, sumexp) partials over chunks of the logits
__global__ void k_lse_partial(const float* __restrict__ logits,
                              float* __restrict__ mpart, float* __restrict__ spart) {
    __shared__ float lm[4], ls[4];
    const int CH = (V + 63) / 64;
    int b = blockIdx.x, t = threadIdx.x;
    int start = b * CH, end = min(start + CH, V);
    float m = -INFINITY, s = 0.f;
    for (int v = start + t; v < end; v += 256) {
        float xv = logits[v];
        if (xv > m) { s = s * expf(m - xv) + 1.f; m = xv; }
        else s += expf(xv - m);
    }
    #pragma unroll
    for (int o = 32; o > 0; o >>= 1) {
        float m2 = __shfl_xor(m, o, 64), s2 = __shfl_xor(s, o, 64);
        float mm = fmaxf(m, m2);
        if (mm > -INFINITY) s = s * expf(m - mm) + s2 * expf(m2 - mm);
        m = mm;
    }
    int wid = t >> 6, lane = t & 63;
    if (lane == 0) { lm[wid] = m; ls[wid] = s; }
    __syncthreads();
    if (t == 0) {
        float M = fmaxf(fmaxf(lm[0], lm[1]), fmaxf(lm[2], lm[3]));
        float S = 0.f;
        if (M > -INFINITY) {
            #pragma unroll
            for (int i = 0; i < 4; ++i) S += ls[i] * expf(lm[i] - M);
        }
        mpart[b] = M; spart[b] = S;
    }
}

// out[v] = logits[v] - logZ, in place
__global__ void k_finalize(const float* __restrict__ mpart, const float* __restrict__ spart,
                           float* __restrict__ out) {
    float m = -INFINITY;
    #pragma unroll 8
    for (int i = 0; i < 64; ++i) m = fmaxf(m, mpart[i]);
    float s = 0.f;
    #pragma unroll 8
    for (int i = 0; i < 64; ++i) s += spart[i] * expf(mpart[i] - m);
    float logZ = m + logf(s);
    int v = blockIdx.x * 256 + threadIdx.x;
    if (v < V) out[v] -= logZ;
}

extern "C" void kernel_launch(void* const* d_in, const int* in_sizes, int n_in,
                              void* d_out, int out_size, void* d_ws, size_t ws_size,
                              hipStream_t stream) {
    const int*   input  = (const int*)  d_in[0];
    const float* hidden = (const float*)d_in[1];
    const float* enc    = (const float*)d_in[2];
    const float* emb    = (const float*)d_in[3];
    const float* attn_w = (const float*)d_in[4];
    const float* attn_b = (const float*)d_in[5];
    const float* comb_w = (const float*)d_in[6];
    const float* comb_b = (const float*)d_in[7];
    const float* w_ih   = (const float*)d_in[8];
    const float* w_hh   = (const float*)d_in[9];
    const float* b_ih   = (const float*)d_in[10];
    const float* b_hh   = (const float*)d_in[11];
    const float* out_w  = (const float*)d_in[12];
    const float* out_b  = (const float*)d_in[13];

    float* out   = (float*)d_out;            // [0, V)      log_softmax
    float* hnew  = out + V;                  // [V, V+H)    h_new
    float* attnw = out + V + H;              // [V+H, +L)   attn_weights

    float* ws           = (float*)d_ws;
    float* scores       = ws;                // 512
    float* partial      = ws + 512;          // 32*1024
    float* attn_applied = ws + 33280;        // 1024
    float* xbuf         = ws + 34304;        // 1024
    float* gi           = ws + 35328;        // 3072
    float* gh           = ws + 38400;        // 3072
    float* mpart        = ws + 41472;        // 64
    float* spart        = ws + 41536;        // 64

    k_scores      <<<512, 256, 0, stream>>>(emb, input, hidden, attn_w, attn_b, scores);
    k_softmax     <<<1, 512, 0, stream>>>(scores, attnw);
    k_attn_partial<<<32, 256, 0, stream>>>(enc, attnw, partial);
    k_attn_reduce <<<4, 256, 0, stream>>>(partial, attn_applied);
    k_combine     <<<1024, 256, 0, stream>>>(emb, input, attn_applied, comb_w, comb_b, xbuf);
    k_gigh        <<<3072, 256, 0, stream>>>(w_ih, w_hh, b_ih, b_hh, xbuf, hidden, gi, gh);
    k_gru         <<<4, 256, 0, stream>>>(gi, gh, hidden, hnew);
    k_logits      <<<2048, 256, 0, stream>>>(out_w, out_b, hnew, out);
    k_lse_partial <<<64, 256, 0, stream>>>(out, mpart, spart);
    k_finalize    <<<(V + 255) / 256, 256, 0, stream>>>(mpart, spart, out);
}

// Round 2
// 61.437 us; speedup vs baseline: 1.1598x; 1.1598x over previous
//
#include <hip/hip_runtime.h>

#define H 1024
#define L 512
#define V 50257
#define LOGIT_BLOCKS 2048   // 4 waves each -> 8192 waves

__device__ __forceinline__ float wave_reduce_sum(float v) {
    #pragma unroll
    for (int o = 32; o > 0; o >>= 1) v += __shfl_xor(v, o, 64);
    return v;
}

// scores[l] = attn_w[l,:1024].e + attn_w[l,1024:].h0 + attn_b[l]
__global__ void k_scores(const float* __restrict__ emb, const int* __restrict__ input,
                         const float* __restrict__ hidden, const float* __restrict__ attn_w,
                         const float* __restrict__ attn_b, float* __restrict__ scores) {
    __shared__ float lds[4];
    int l = blockIdx.x, t = threadIdx.x;
    size_t erow = (size_t)input[0] * H;
    const float4* w = (const float4*)(attn_w + (size_t)l * 2 * H);
    float4 a  = w[t];
    float4 b  = w[256 + t];
    float4 ev = ((const float4*)(emb + erow))[t];
    float4 hv = ((const float4*)hidden)[t];
    float acc = a.x*ev.x + a.y*ev.y + a.z*ev.z + a.w*ev.w
              + b.x*hv.x + b.y*hv.y + b.z*hv.z + b.w*hv.w;
    acc = wave_reduce_sum(acc);
    int wid = t >> 6, lane = t & 63;
    if (lane == 0) lds[wid] = acc;
    __syncthreads();
    if (t == 0) scores[l] = lds[0] + lds[1] + lds[2] + lds[3] + attn_b[l];
}

// fused: softmax(scores) -> attn_weights (block 0 writes output copy),
// then attn_applied[col] = sum_l w[l]*enc[l][col]; block handles 16 cols
__global__ void k_attn(const float* __restrict__ scores, const float* __restrict__ enc,
                       float* __restrict__ attn_out, float* __restrict__ attn_applied) {
    __shared__ float w[512];
    __shared__ float red[4];
    __shared__ float acc_lds[256];
    __shared__ float sM, sS;
    int t = threadIdx.x, lane = t & 63, wid = t >> 6;
    float s0 = scores[t], s1 = scores[t + 256];
    float m = fmaxf(s0, s1);
    #pragma unroll
    for (int o = 32; o > 0; o >>= 1) m = fmaxf(m, __shfl_xor(m, o, 64));
    if (lane == 0) red[wid] = m;
    __syncthreads();
    if (t == 0) sM = fmaxf(fmaxf(red[0], red[1]), fmaxf(red[2], red[3]));
    __syncthreads();
    float M = sM;
    float e0 = expf(s0 - M), e1 = expf(s1 - M);
    float s = e0 + e1;
    s = wave_reduce_sum(s);
    if (lane == 0) red[wid] = s;
    __syncthreads();
    if (t == 0) sS = red[0] + red[1] + red[2] + red[3];
    __syncthreads();
    float inv = 1.f / sS;
    w[t] = e0 * inv; w[t + 256] = e1 * inv;
    __syncthreads();
    if (blockIdx.x == 0) { attn_out[t] = w[t]; attn_out[t + 256] = w[t + 256]; }
    // weighted sum over encoder rows for this block's 16 columns
    int col = blockIdx.x * 16 + (t & 15);
    int rc  = t >> 4;                       // row chunk 0..15
    float acc = 0.f;
    #pragma unroll 8
    for (int l = rc; l < 512; l += 16)
        acc += w[l] * enc[(size_t)l * H + col];
    acc_lds[t] = acc;
    __syncthreads();
    #pragma unroll
    for (int st = 128; st >= 16; st >>= 1) {
        if (t < st) acc_lds[t] += acc_lds[t + st];
        __syncthreads();
    }
    if (t < 16) attn_applied[blockIdx.x * 16 + t] = acc_lds[t];
}

// x[h] = relu(comb_w[h,:1024].e + comb_w[h,1024:].attn_applied + comb_b[h])
__global__ void k_combine(const float* __restrict__ emb, const int* __restrict__ input,
                          const float* __restrict__ attn_applied, const float* __restrict__ comb_w,
                          const float* __restrict__ comb_b, float* __restrict__ x) {
    __shared__ float lds[4];
    int h = blockIdx.x, t = threadIdx.x;
    size_t erow = (size_t)input[0] * H;
    const float4* w = (const float4*)(comb_w + (size_t)h * 2 * H);
    float4 a  = w[t];
    float4 b  = w[256 + t];
    float4 ev = ((const float4*)(emb + erow))[t];
    float4 av = ((const float4*)attn_applied)[t];
    float acc = a.x*ev.x + a.y*ev.y + a.z*ev.z + a.w*ev.w
              + b.x*av.x + b.y*av.y + b.z*av.z + b.w*av.w;
    acc = wave_reduce_sum(acc);
    int wid = t >> 6, lane = t & 63;
    if (lane == 0) lds[wid] = acc;
    __syncthreads();
    if (t == 0) x[h] = fmaxf(lds[0] + lds[1] + lds[2] + lds[3] + comb_b[h], 0.f);
}

// block h: all 6 gate dot-products + GRU update -> hnew[h]
__global__ void k_gru_fused(const float* __restrict__ w_ih, const float* __restrict__ w_hh,
                            const float* __restrict__ b_ih, const float* __restrict__ b_hh,
                            const float* __restrict__ x, const float* __restrict__ hidden,
                            float* __restrict__ hnew) {
    __shared__ float lds[4][6];
    int h = blockIdx.x, t = threadIdx.x, lane = t & 63, wid = t >> 6;
    float4 xv = ((const float4*)x)[t];
    float4 hv = ((const float4*)hidden)[t];
    const float* rows[6] = {
        w_ih + (size_t)h * H, w_ih + (size_t)(H + h) * H, w_ih + (size_t)(2 * H + h) * H,
        w_hh + (size_t)h * H, w_hh + (size_t)(H + h) * H, w_hh + (size_t)(2 * H + h) * H };
    float acc[6];
    #pragma unroll
    for (int k = 0; k < 6; ++k) {
        float4 wv = ((const float4*)rows[k])[t];
        float4 v  = (k < 3) ? xv : hv;
        acc[k] = wv.x*v.x + wv.y*v.y + wv.z*v.z + wv.w*v.w;
        acc[k] = wave_reduce_sum(acc[k]);
    }
    if (lane == 0) {
        #pragma unroll
        for (int k = 0; k < 6; ++k) lds[wid][k] = acc[k];
    }
    __syncthreads();
    if (t == 0) {
        float g[6];
        #pragma unroll
        for (int k = 0; k < 6; ++k) g[k] = lds[0][k] + lds[1][k] + lds[2][k] + lds[3][k];
        float ir = g[0] + b_ih[h],         hr = g[3] + b_hh[h];
        float iz = g[1] + b_ih[H + h],     hz = g[4] + b_hh[H + h];
        float in_ = g[2] + b_ih[2 * H + h], hn = g[5] + b_hh[2 * H + h];
        float r = 1.f / (1.f + expf(-(ir + hr)));
        float z = 1.f / (1.f + expf(-(iz + hz)));
        float n = tanhf(in_ + r * hn);
        hnew[h] = (1.f - z) * n + z * hidden[h];
    }
}

// logits + per-block online (m, sumexp) partial
__global__ void k_logits_lse(const float* __restrict__ out_w, const float* __restrict__ out_b,
                             const float* __restrict__ hvec, float* __restrict__ logits,
                             float* __restrict__ mpart, float* __restrict__ spart) {
    __shared__ float lm[4], ls[4];
    int lane = threadIdx.x & 63, wid = threadIdx.x >> 6;
    int gwave = blockIdx.x * 4 + wid;
    const int nwaves = LOGIT_BLOCKS * 4;
    float4 h4[4];
    #pragma unroll
    for (int j = 0; j < 4; ++j) h4[j] = ((const float4*)hvec)[j * 64 + lane];
    float m = -INFINITY, s = 0.f;
    for (int r = gwave; r < V; r += nwaves) {
        const float4* row = (const float4*)(out_w + (size_t)r * H);
        float acc = 0.f;
        #pragma unroll
        for (int j = 0; j < 4; ++j) {
            float4 a = row[j * 64 + lane];
            acc += a.x*h4[j].x + a.y*h4[j].y + a.z*h4[j].z + a.w*h4[j].w;
        }
        acc = wave_reduce_sum(acc);            // all lanes hold the sum
        float logit = acc + out_b[r];          // same-address broadcast load
        if (lane == 0) logits[r] = logit;
        if (logit > m) { s = s * expf(m - logit) + 1.f; m = logit; }
        else           { s += expf(logit - m); }
    }
    if (lane == 0) { lm[wid] = m; ls[wid] = s; }
    __syncthreads();
    if (threadIdx.x == 0) {
        float M = fmaxf(fmaxf(lm[0], lm[1]), fmaxf(lm[2], lm[3]));
        float S = 0.f;
        if (M > -INFINITY) {
            #pragma unroll
            for (int i = 0; i < 4; ++i) S += ls[i] * expf(lm[i] - M);
        }
        mpart[blockIdx.x] = M; spart[blockIdx.x] = S;
    }
}

// each block redundantly merges the 2048 partials, then subtracts logZ in place
__global__ void k_finalize(const float* __restrict__ mpart, const float* __restrict__ spart,
                           float* __restrict__ out) {
    __shared__ float lm[4], ls[4];
    __shared__ float sLogZ;
    int t = threadIdx.x, lane = t & 63, wid = t >> 6;
    float m = -INFINITY, s = 0.f;
    for (int i = t; i < LOGIT_BLOCKS; i += 256) {
        float m2 = mpart[i], s2 = spart[i];
        float mm = fmaxf(m, m2);
        if (mm > -INFINITY) s = s * expf(m - mm) + s2 * expf(m2 - mm);
        m = mm;
    }
    #pragma unroll
    for (int o = 32; o > 0; o >>= 1) {
        float m2 = __shfl_xor(m, o, 64), s2 = __shfl_xor(s, o, 64);
        float mm = fmaxf(m, m2);
        if (mm > -INFINITY) s = s * expf(m - mm) + s2 * expf(m2 - mm);
        m = mm;
    }
    if (lane == 0) { lm[wid] = m; ls[wid] = s; }
    __syncthreads();
    if (t == 0) {
        float M = fmaxf(fmaxf(lm[0], lm[1]), fmaxf(lm[2], lm[3]));
        float S = 0.f;
        #pragma unroll
        for (int i = 0; i < 4; ++i) S += ls[i] * expf(lm[i] - M);
        sLogZ = M + logf(S);
    }
    __syncthreads();
    int v = blockIdx.x * 256 + t;
    if (v < V) out[v] -= sLogZ;
}

extern "C" void kernel_launch(void* const* d_in, const int* in_sizes, int n_in,
                              void* d_out, int out_size, void* d_ws, size_t ws_size,
                              hipStream_t stream) {
    const int*   input  = (const int*)  d_in[0];
    const float* hidden = (const float*)d_in[1];
    const float* enc    = (const float*)d_in[2];
    const float* emb    = (const float*)d_in[3];
    const float* attn_w = (const float*)d_in[4];
    const float* attn_b = (const float*)d_in[5];
    const float* comb_w = (const float*)d_in[6];
    const float* comb_b = (const float*)d_in[7];
    const float* w_ih   = (const float*)d_in[8];
    const float* w_hh   = (const float*)d_in[9];
    const float* b_ih   = (const float*)d_in[10];
    const float* b_hh   = (const float*)d_in[11];
    const float* out_w  = (const float*)d_in[12];
    const float* out_b  = (const float*)d_in[13];

    float* out   = (float*)d_out;            // [0, V)      log_softmax
    float* hnew  = out + V;                  // [V, V+H)    h_new
    float* attnw = out + V + H;              // [V+H, +L)   attn_weights

    float* ws           = (float*)d_ws;
    float* scores       = ws;                // 512
    float* attn_applied = ws + 512;          // 1024
    float* xbuf         = ws + 1536;         // 1024
    float* mpart        = ws + 2560;         // 2048
    float* spart        = ws + 4608;         // 2048

    k_scores     <<<512, 256, 0, stream>>>(emb, input, hidden, attn_w, attn_b, scores);
    k_attn       <<<64, 256, 0, stream>>>(scores, enc, attnw, attn_applied);
    k_combine    <<<1024, 256, 0, stream>>>(emb, input, attn_applied, comb_w, comb_b, xbuf);
    k_gru_fused  <<<1024, 256, 0, stream>>>(w_ih, w_hh, b_ih, b_hh, xbuf, hidden, hnew);
    k_logits_lse <<<LOGIT_BLOCKS, 256, 0, stream>>>(out_w, out_b, hnew, out, mpart, spart);
    k_finalize   <<<(V + 255) / 256, 256, 0, stream>>>(mpart, spart, out);
}